// Round 17
// baseline (288.060 us; speedup 1.0000x reference)
//
#include <hip/hip_runtime.h>
#include <math.h>

// VolumeSDFRenderer — pinned fp32 np-order pipeline; element-127 cumsum via
// XLA ReduceWindowRewriter (base_length=16) two-level shape:
//   chunks of 16, SEQUENTIAL within chunk; chunk sums scanned sequentially;
//   outer prefix added ONCE:
//     y127 = fl( fl(L + x127) + P7 ),  L  = chain(x112..x126),
//                                      P7 = ((S0+S1)+..)+S6 (chunk sums)
//     t127 = y127 - x127   ->  TWO independent quantizations on ulp(x127):
//            absorb <=> L < half-ulp AND P7 < half-ulp.
//
// Why (R11/R13/R15/R16 jointly): seq(k=1) fails; full-KS(k=7) fails;
// warp96(k=6) fails SMALL (0.9961 = few-hundred-ray cohort diff); probed
// ray (tree-yes/seq-no/warp96-no) NOT absorbed by ref. cohort(seq) c
// cohort(base16) c cohort(warp96) c cohort(tree): base16 is the unique
// remaining canonical shape — and it's the actual XLA pass jnp.cumsum hits.
//
// p<=126: R11's pinned sequential chain (no huge absorber; bracketing diffs
// ~1e-6 << 0.0392 threshold). Pins (asm value-barriers) on x, C, t forbid
// fma-contraction of C+x (rounds 3-10's inf factory), (C+x)-x folding
// (artifact deletion), and exp-argument distribution.

#define N_PTS 128
#define PIN(v) asm volatile("" : "+v"(v))

__global__ __launch_bounds__(256) void vr17_base16(
    const float* __restrict__ distance,
    const float* __restrict__ color,
    const float* __restrict__ depth,
    float* __restrict__ out,
    int n_rays)
{
    int ray = blockIdx.x * 256 + threadIdx.x;
    if (ray >= n_rays) return;

    const float* dr = distance + (size_t)ray * N_PTS;
    const float* zr = depth    + (size_t)ray * N_PTS;
    const float* cw = color    + (size_t)ray * (3 * N_PTS);

    float C  = 0.0f;                 // sequential cumsum (weights p<=126)
    float ar = 0.0f, ag = 0.0f, ab = 0.0f;
    float P7 = 0.0f;                 // scanned chunk-sum prefix, chunks 0..6
    float Sc = 0.0f;                 // current chunk partial sum
    float L  = 0.0f;                 // within-chunk-7 prefix: x112..x126

    for (int p = 0; p < N_PTS - 1; ++p) {
        float d     = dr[p];
        float e     = expf(-150.0f * d);
        float num   = 150.0f * e;
        float o     = 1.0f + e;
        float sq    = o * o;
        float den   = num / sq;               // np op order; /inf -> +0
        float delta = zr[p + 1] - zr[p];

        float x = delta * den;                // single rounded multiply
        PIN(x);                               // no fma contraction

        C = C + x;                            // sequential cumsum
        PIN(C);                               // no (C+x)-x fold
        float t = C - x;
        PIN(t);                               // opaque exp argument

        float T = expf(-t);                   // <= 1
        float w = T * (1.0f - expf(-x));      // in [0,1]
        PIN(w);

        ar += w * cw[3 * p + 0];
        ag += w * cw[3 * p + 1];
        ab += w * cw[3 * p + 2];

        // ReduceWindowRewriter bookkeeping for element 127:
        if (p < 112) {
            Sc = Sc + x; PIN(Sc);             // sequential within chunk
            if ((p & 15) == 15) {             // chunk complete
                P7 = P7 + Sc; PIN(P7);        // sequential scan of chunk sums
                Sc = 0.0f;
            }
        } else {
            L = L + x; PIN(L);                // chunk-7 local prefix
        }
    }

    // ---- p = 127: two-level chunked cumsum ----
    {
        float d   = dr[N_PTS - 1];
        float e   = expf(-150.0f * d);
        float num = 150.0f * e;
        float o   = 1.0f + e;
        float sq  = o * o;
        float den = num / sq;
        float x   = 1e10f * den;              // up to ~3.75e11
        PIN(x);

        float y = L + x;                      // within-chunk: fl(L + x127)
        PIN(y);
        y = y + P7;                           // outer prefix: ONE add
        PIN(y);

        float t = y - x;                      // exact (y within 2x of x)
        PIN(t);

        float T = expf(-t);
        float w = T * (1.0f - expf(-x));
        PIN(w);

        ar += w * cw[3 * (N_PTS - 1) + 0];
        ag += w * cw[3 * (N_PTS - 1) + 1];
        ab += w * cw[3 * (N_PTS - 1) + 2];
    }

    // No-op for correct results (sum w <= 2, c < 1); keeps any residual
    // fault finite and diagnosable.
    out[(size_t)ray * 3 + 0] = fminf(fmaxf(ar, 0.0f), 2.5f);
    out[(size_t)ray * 3 + 1] = fminf(fmaxf(ag, 0.0f), 2.5f);
    out[(size_t)ray * 3 + 2] = fminf(fmaxf(ab, 0.0f), 2.5f);
}

extern "C" void kernel_launch(void* const* d_in, const int* in_sizes, int n_in,
                              void* d_out, int out_size, void* d_ws, size_t ws_size,
                              hipStream_t stream) {
    const float* distance = (const float*)d_in[0];
    const float* color    = (const float*)d_in[1];
    const float* depth    = (const float*)d_in[2];
    float* out = (float*)d_out;

    const int n_rays  = in_sizes[0] / N_PTS;                // 65536
    const int threads = 256;
    const int blocks  = (n_rays + threads - 1) / threads;   // 256

    hipLaunchKernelGGL(vr17_base16, dim3(blocks), dim3(threads), 0,
                       stream, distance, color, depth, out, n_rays);
}

// Round 18
// 59.150 us; speedup vs baseline: 4.8700x; 4.8700x over previous
//
#include <hip/hip_runtime.h>
#include <math.h>

// VolumeSDFRenderer — wave-per-ray, coalesced; element-127 absorb chain
// bit-identical to the PASSING R17 kernel (XLA ReduceWindowRewriter base-16:
// chunks of 16 sequential, chunk sums scanned sequentially, outer prefix
// added once):  y127 = fl(fl(L + x127) + P7), t127 = y127 - x127.
//
// R17 passed at absmax 0.0039 but ran 137.8 us: thread-per-ray = 1024 waves
// chip-wide (10.8% occupancy) + 512B-stride uncoalesced reads -> latency-
// bound at 10.6% HBM. This kernel: one WAVE per ray (65536 waves), lane l
// owns points 2l,2l+1 (float2 loads, coalesced), shuffle scan for the
// smooth exclusive prefix (assoc-insensitive, ~1e-6 << 0.0392 threshold).
//
// BIT-CRITICAL (kept identical to R17): per-point x = delta*den chain
// (OCML expf, np op order, PIN after the mul -> no fma contraction), and
// the element-127 cascade (x's staged to LDS, S_c/P7/L re-accumulated in
// R17's exact sequential order with PIN after every add, then
// y=L+x127 / y+=P7 / t=y-x127, each PINned). PINs forbid the
// -ffp-contract fma fusion + reassociation that produced rounds 3-10's
// inf/clamp-sat and round 7's artifact deletion.

#define N_PTS 128
#define PIN(v) asm volatile("" : "+v"(v))

__global__ __launch_bounds__(256) void vr18_wave(
    const float* __restrict__ distance,
    const float* __restrict__ color,
    const float* __restrict__ depth,
    float* __restrict__ out,
    int n_rays)
{
    const int lane = threadIdx.x & 63;
    const int wv   = threadIdx.x >> 6;
    const int ray  = blockIdx.x * 4 + wv;
    if (ray >= n_rays) return;

    __shared__ float xbuf[4][N_PTS];

    // ---- coalesced loads ----
    const float2* dist2 = (const float2*)(distance + (size_t)ray * N_PTS);
    const float2* dep2  = (const float2*)(depth    + (size_t)ray * N_PTS);
    float2 dv = dist2[lane];
    float2 zv = dep2[lane];

    // ---- density + x, BIT-IDENTICAL op order to R17 ----
    float e0 = expf(-150.0f * dv.x);
    float n0 = 150.0f * e0;
    float o0 = 1.0f + e0;
    float q0 = o0 * o0;
    float den0 = n0 / q0;

    float e1 = expf(-150.0f * dv.y);
    float n1 = 150.0f * e1;
    float o1 = 1.0f + e1;
    float q1 = o1 * o1;
    float den1 = n1 / q1;

    float znext = __shfl_down(zv.x, 1);
    float d0 = zv.y - zv.x;                       // delta[2l]
    float d1 = (lane == 63) ? 1e10f : (znext - zv.y);

    float x0 = d0 * den0; PIN(x0);                // no fma contraction
    float x1 = d1 * den1; PIN(x1);                // lane63: x127 (huge)

    // ---- stage x to LDS for the bit-exact element-127 cascade ----
    xbuf[wv][2 * lane]     = x0;
    xbuf[wv][2 * lane + 1] = x1;
    __syncthreads();

    // ---- smooth exclusive prefix via wave scan (excl ~1e-6 of ref) ----
    float sscan = (lane == 63) ? x0 : (x0 + x1);  // exclude huge x127
    float incl = sscan;
    #pragma unroll
    for (int off = 1; off < 64; off <<= 1) {
        float t = __shfl_up(incl, off);
        if (lane >= off) incl += t;
    }
    float vprev = __shfl_up(incl, 1);
    float excl = (lane == 0) ? 0.0f : vprev;      // sum x[0..2l-1]

    float Ta = expf(-excl);
    float wa = Ta * (1.0f - expf(-x0));
    float Tb = expf(-(excl + x0));
    float wb = Tb * (1.0f - expf(-x1));           // lane63 overridden below

    // ---- element 127: R17's exact base-16 cascade (all lanes, lockstep;
    //      LDS reads are uniform-address broadcasts) ----
    {
        float P7 = 0.0f, Sc = 0.0f;
        #pragma unroll
        for (int c = 0; c < 7; ++c) {
            Sc = 0.0f;
            #pragma unroll
            for (int i = 0; i < 16; ++i) {
                Sc = Sc + xbuf[wv][16 * c + i]; PIN(Sc);
            }
            P7 = P7 + Sc; PIN(P7);
        }
        float L = 0.0f;
        #pragma unroll
        for (int i = 112; i < 127; ++i) {
            L = L + xbuf[wv][i]; PIN(L);
        }
        float x127 = __shfl(x1, 63);
        float y = L + x127; PIN(y);               // within-chunk add
        y = y + P7;         PIN(y);               // outer prefix: ONE add
        float t = y - x127; PIN(t);               // opaque exp argument
        float T127 = expf(-t);
        float w127 = T127 * (1.0f - expf(-x127));
        if (lane == 63) wb = w127;
    }

    // ---- color (3 ch x 2 pts = 3x float2 per lane, coalesced) ----
    const float2* col2 = (const float2*)(color + (size_t)ray * 384 + lane * 6);
    float2 c0 = col2[0];   // p0.r, p0.g
    float2 c1 = col2[1];   // p0.b, p1.r
    float2 c2 = col2[2];   // p1.g, p1.b
    float r = wa * c0.x + wb * c1.y;
    float g = wa * c0.y + wb * c2.x;
    float b = wa * c1.x + wb * c2.y;

    // ---- wave butterfly reduction ----
    #pragma unroll
    for (int off = 32; off >= 1; off >>= 1) {
        r += __shfl_xor(r, off);
        g += __shfl_xor(g, off);
        b += __shfl_xor(b, off);
    }

    if (lane == 0) {
        float* o = out + (size_t)ray * 3;
        o[0] = fminf(fmaxf(r, 0.0f), 2.5f);       // no-op clamp (sum w <= 2)
        o[1] = fminf(fmaxf(g, 0.0f), 2.5f);
        o[2] = fminf(fmaxf(b, 0.0f), 2.5f);
    }
}

extern "C" void kernel_launch(void* const* d_in, const int* in_sizes, int n_in,
                              void* d_out, int out_size, void* d_ws, size_t ws_size,
                              hipStream_t stream) {
    const float* distance = (const float*)d_in[0];
    const float* color    = (const float*)d_in[1];
    const float* depth    = (const float*)d_in[2];
    float* out = (float*)d_out;

    const int n_rays = in_sizes[0] / N_PTS;        // 65536
    const int blocks = (n_rays + 3) / 4;           // 4 rays (waves) / block

    hipLaunchKernelGGL(vr18_wave, dim3(blocks), dim3(256), 0, stream,
                       distance, color, depth, out, n_rays);
}

// Round 19
// 38.893 us; speedup vs baseline: 7.4065x; 1.5209x over previous
//
#include <hip/hip_runtime.h>
#include <math.h>

// VolumeSDFRenderer — wave-per-ray; distributed bit-exact base-16 cascade.
//
// Reference semantics (proven R17/R18, absmax 0.0039): XLA base-16 two-level
// cumsum at element 127: y = fl(fl(L + x127) + P7), t = y - x127, with
// L = seq(x112..x126), P7 = seq chunk-sum scan (chunks of 16, seq within).
// All absorb-critical arithmetic (density expf -> x -> chunk sums -> L,P7 ->
// y,t) is OCML expf + PINned fp32, bit-identical add ORDER to R17.
//
// R18 was VALU-bound (VALUBusy 64%, HBM 15% with inputs L3-resident):
//  (1) cascade was a 127-step serial PINned add chain -> now DISTRIBUTED:
//      lane l computes chunk sum S_{l&7} (16 serial adds, same order),
//      shfl-gather S0..S6 -> P7 (7 adds); L (15 adds) in parallel.
//      Serial depth 127 -> ~38. LDS padded +1/16 so the 8 chunk streams
//      hit 8 distinct banks.
//  (2) smooth-path exps (weights) use __expf, and Tb = Ta*E0 replaces an
//      expf entirely: 8 OCML expf/lane -> 2 OCML + 4 fast. Effect ~1e-6,
//      threshold 0.0392.
// PINs forbid -ffp-contract fma fusion ((C+x)->fma while t=C-x subtracts the
// separately-rounded x: the inf factory of rounds 3-10) and reassociation.

#define N_PTS 128
#define PIN(v) asm volatile("" : "+v"(v))
#define XIDX(p) ((p) + ((p) >> 4))     // +1 pad per 16: chunk c starts at 17c

__global__ __launch_bounds__(256) void vr19_dist(
    const float* __restrict__ distance,
    const float* __restrict__ color,
    const float* __restrict__ depth,
    float* __restrict__ out,
    int n_rays)
{
    const int lane = threadIdx.x & 63;
    const int wv   = threadIdx.x >> 6;
    const int ray  = blockIdx.x * 4 + wv;
    if (ray >= n_rays) return;

    __shared__ float xbuf[4][136];

    // ---- coalesced loads ----
    const float2* dist2 = (const float2*)(distance + (size_t)ray * N_PTS);
    const float2* dep2  = (const float2*)(depth    + (size_t)ray * N_PTS);
    float2 dv = dist2[lane];
    float2 zv = dep2[lane];

    // ---- density + x: BIT-IDENTICAL chain to R17 (OCML expf, PINned mul) --
    float e0 = expf(-150.0f * dv.x);
    float n0 = 150.0f * e0;
    float o0 = 1.0f + e0;
    float q0 = o0 * o0;
    float den0 = n0 / q0;

    float e1 = expf(-150.0f * dv.y);
    float n1 = 150.0f * e1;
    float o1 = 1.0f + e1;
    float q1 = o1 * o1;
    float den1 = n1 / q1;

    float znext = __shfl_down(zv.x, 1);
    float d0 = zv.y - zv.x;
    float d1 = (lane == 63) ? 1e10f : (znext - zv.y);

    float x0 = d0 * den0; PIN(x0);
    float x1 = d1 * den1; PIN(x1);                // lane63: x127 (huge)

    // ---- stage x to padded LDS ----
    xbuf[wv][XIDX(2 * lane)]     = x0;
    xbuf[wv][XIDX(2 * lane + 1)] = x1;
    __syncthreads();

    // ---- smooth exclusive prefix (wave scan; assoc-insensitive) ----
    float sscan = (lane == 63) ? x0 : (x0 + x1);
    float incl = sscan;
    #pragma unroll
    for (int off = 1; off < 64; off <<= 1) {
        float t = __shfl_up(incl, off);
        if (lane >= off) incl += t;
    }
    float vprev = __shfl_up(incl, 1);
    float excl = (lane == 0) ? 0.0f : vprev;

    // ---- weights (smooth path: fast exp; ~1e-6 of ref) ----
    float Ta = __expf(-excl);
    float E0 = __expf(-x0);
    float E1 = __expf(-x1);                       // lane63: exp(-x127) -> ok
    float Tb = Ta * E0;
    float wa = Ta * (1.0f - E0);
    float wb = Tb * (1.0f - E1);                  // lane63 overridden below

    // ---- element 127: bit-exact base-16 cascade, DISTRIBUTED ----
    {
        // lane l computes chunk sum S_{l&7}: 16 serial PINned adds
        // (bit-identical order; padded LDS -> 8 distinct banks).
        const int c = lane & 7;
        float S = 0.0f;
        #pragma unroll
        for (int i = 0; i < 16; ++i) {
            S = S + xbuf[wv][17 * c + i]; PIN(S);
        }
        // P7 = sequential scan of S0..S6 (shfl-gather in order)
        float P7 = 0.0f;
        #pragma unroll
        for (int cc = 0; cc < 7; ++cc) {
            float Sc = __shfl(S, cc);
            P7 = P7 + Sc; PIN(P7);
        }
        // L = sequential x112..x126 (broadcast reads)
        float L = 0.0f;
        #pragma unroll
        for (int p = 112; p < 127; ++p) {
            L = L + xbuf[wv][XIDX(p)]; PIN(L);
        }
        float x127 = __shfl(x1, 63);
        float y = L + x127; PIN(y);               // within-chunk add
        y = y + P7;         PIN(y);               // outer prefix: ONE add
        float t = y - x127; PIN(t);               // opaque exp argument
        float T127 = __expf(-t);                  // smooth in t
        float w127 = T127 * (1.0f - E1);          // E1(lane63) = exp(-x127)
        if (lane == 63) wb = w127;
    }

    // ---- color (3 ch x 2 pts = 3x float2 per lane) ----
    const float2* col2 = (const float2*)(color + (size_t)ray * 384 + lane * 6);
    float2 c0 = col2[0];
    float2 c1 = col2[1];
    float2 c2 = col2[2];
    float r = wa * c0.x + wb * c1.y;
    float g = wa * c0.y + wb * c2.x;
    float b = wa * c1.x + wb * c2.y;

    // ---- wave butterfly reduction ----
    #pragma unroll
    for (int off = 32; off >= 1; off >>= 1) {
        r += __shfl_xor(r, off);
        g += __shfl_xor(g, off);
        b += __shfl_xor(b, off);
    }

    if (lane == 0) {
        float* o = out + (size_t)ray * 3;
        o[0] = fminf(fmaxf(r, 0.0f), 2.5f);       // no-op clamp (sum w <= 2)
        o[1] = fminf(fmaxf(g, 0.0f), 2.5f);
        o[2] = fminf(fmaxf(b, 0.0f), 2.5f);
    }
}

extern "C" void kernel_launch(void* const* d_in, const int* in_sizes, int n_in,
                              void* d_out, int out_size, void* d_ws, size_t ws_size,
                              hipStream_t stream) {
    const float* distance = (const float*)d_in[0];
    const float* color    = (const float*)d_in[1];
    const float* depth    = (const float*)d_in[2];
    float* out = (float*)d_out;

    const int n_rays = in_sizes[0] / N_PTS;        // 65536
    const int blocks = (n_rays + 3) / 4;           // 4 rays (waves) / block

    hipLaunchKernelGGL(vr19_dist, dim3(blocks), dim3(256), 0, stream,
                       distance, color, depth, out, n_rays);
}

// Round 20
// 38.718 us; speedup vs baseline: 7.4399x; 1.0045x over previous
//
#include <hip/hip_runtime.h>
#include <math.h>

// VolumeSDFRenderer — wave-per-ray; distributed bit-order-exact base-16
// cascade; all-hardware exp (v_exp_f32).
//
// Reference semantics (R17/R18/R19 passed, absmax = bf16 comparator floor):
// XLA base-16 two-level cumsum at element 127: y = fl(fl(L+x127)+P7),
// t = y-x127; L = seq(x112..x126), P7 = seq scan of 16-elem chunk sums.
// What must be preserved is the ADD ORDER (structure) of the absorb chain —
// PINs forbid -ffp-contract fma fusion (rounds 3-10's inf factory),
// (C+x)-x folding, and exp-arg distribution. 1-2 ulp value perturbations
// from __expf vs OCML expf move L/P7 by ~1e-7 relative; expected absorb
// flips ~1e-3 rays over the dataset — negligible risk, and OCML's divergent
// slow paths (args span +-1500 here) cost ~20+ VALU ops per call.
//
// R19 -> R20: (1) ALL exps -> __expf (branch-free v_exp_f32);
// (2) __syncthreads removed — each wave reads only its private xbuf[wv]
// slice and same-wave LDS ops are ordered (lgkmcnt waits auto-inserted);
// loads can now hoist freely.

#define N_PTS 128
#define PIN(v) asm volatile("" : "+v"(v))
#define XIDX(p) ((p) + ((p) >> 4))     // +1 pad per 16: chunk c starts at 17c

__global__ __launch_bounds__(256) void vr20_fastexp(
    const float* __restrict__ distance,
    const float* __restrict__ color,
    const float* __restrict__ depth,
    float* __restrict__ out,
    int n_rays)
{
    const int lane = threadIdx.x & 63;
    const int wv   = threadIdx.x >> 6;
    const int ray  = blockIdx.x * 4 + wv;
    if (ray >= n_rays) return;

    __shared__ float xbuf[4][136];

    // ---- coalesced loads ----
    const float2* dist2 = (const float2*)(distance + (size_t)ray * N_PTS);
    const float2* dep2  = (const float2*)(depth    + (size_t)ray * N_PTS);
    float2 dv = dist2[lane];
    float2 zv = dep2[lane];

    // ---- density + x: same op ORDER as R17 (hw exp; PINned mul) ----
    float e0 = __expf(-150.0f * dv.x);
    float n0 = 150.0f * e0;
    float o0 = 1.0f + e0;
    float q0 = o0 * o0;
    float den0 = n0 / q0;                         // /inf -> +0 (np regime)

    float e1 = __expf(-150.0f * dv.y);
    float n1 = 150.0f * e1;
    float o1 = 1.0f + e1;
    float q1 = o1 * o1;
    float den1 = n1 / q1;

    float znext = __shfl_down(zv.x, 1);
    float d0 = zv.y - zv.x;
    float d1 = (lane == 63) ? 1e10f : (znext - zv.y);

    float x0 = d0 * den0; PIN(x0);                // no fma contraction
    float x1 = d1 * den1; PIN(x1);                // lane63: x127 (huge)

    // ---- stage x to padded LDS (wave-private slice; no barrier needed) ----
    xbuf[wv][XIDX(2 * lane)]     = x0;
    xbuf[wv][XIDX(2 * lane + 1)] = x1;

    // ---- smooth exclusive prefix (wave scan; assoc-insensitive) ----
    float sscan = (lane == 63) ? x0 : (x0 + x1);
    float incl = sscan;
    #pragma unroll
    for (int off = 1; off < 64; off <<= 1) {
        float t = __shfl_up(incl, off);
        if (lane >= off) incl += t;
    }
    float vprev = __shfl_up(incl, 1);
    float excl = (lane == 0) ? 0.0f : vprev;

    // ---- weights (smooth path) ----
    float Ta = __expf(-excl);
    float E0 = __expf(-x0);
    float E1 = __expf(-x1);                       // lane63: exp(-x127)
    float Tb = Ta * E0;
    float wa = Ta * (1.0f - E0);
    float wb = Tb * (1.0f - E1);                  // lane63 overridden below

    // ---- element 127: base-16 cascade, order-exact, distributed ----
    {
        const int c = lane & 7;                   // lane computes S_{l&7}
        float S = 0.0f;
        #pragma unroll
        for (int i = 0; i < 16; ++i) {
            S = S + xbuf[wv][17 * c + i]; PIN(S);
        }
        float P7 = 0.0f;                          // seq scan of S0..S6
        #pragma unroll
        for (int cc = 0; cc < 7; ++cc) {
            float Sc = __shfl(S, cc);
            P7 = P7 + Sc; PIN(P7);
        }
        float L = 0.0f;                           // seq x112..x126
        #pragma unroll
        for (int p = 112; p < 127; ++p) {
            L = L + xbuf[wv][XIDX(p)]; PIN(L);
        }
        float x127 = __shfl(x1, 63);
        float y = L + x127; PIN(y);               // within-chunk add
        y = y + P7;         PIN(y);               // outer prefix: ONE add
        float t = y - x127; PIN(t);               // opaque exp argument
        float T127 = __expf(-t);
        float w127 = T127 * (1.0f - E1);          // E1(lane63)=exp(-x127)
        if (lane == 63) wb = w127;
    }

    // ---- color (3 ch x 2 pts = 3x float2 per lane) ----
    const float2* col2 = (const float2*)(color + (size_t)ray * 384 + lane * 6);
    float2 c0 = col2[0];
    float2 c1 = col2[1];
    float2 c2 = col2[2];
    float r = wa * c0.x + wb * c1.y;
    float g = wa * c0.y + wb * c2.x;
    float b = wa * c1.x + wb * c2.y;

    // ---- wave butterfly reduction ----
    #pragma unroll
    for (int off = 32; off >= 1; off >>= 1) {
        r += __shfl_xor(r, off);
        g += __shfl_xor(g, off);
        b += __shfl_xor(b, off);
    }

    if (lane == 0) {
        float* o = out + (size_t)ray * 3;
        o[0] = fminf(fmaxf(r, 0.0f), 2.5f);       // no-op clamp (sum w <= 2)
        o[1] = fminf(fmaxf(g, 0.0f), 2.5f);
        o[2] = fminf(fmaxf(b, 0.0f), 2.5f);
    }
}

extern "C" void kernel_launch(void* const* d_in, const int* in_sizes, int n_in,
                              void* d_out, int out_size, void* d_ws, size_t ws_size,
                              hipStream_t stream) {
    const float* distance = (const float*)d_in[0];
    const float* color    = (const float*)d_in[1];
    const float* depth    = (const float*)d_in[2];
    float* out = (float*)d_out;

    const int n_rays = in_sizes[0] / N_PTS;        // 65536
    const int blocks = (n_rays + 3) / 4;           // 4 rays (waves) / block

    hipLaunchKernelGGL(vr20_fastexp, dim3(blocks), dim3(256), 0, stream,
                       distance, color, depth, out, n_rays);
}

// Round 21
// 30.767 us; speedup vs baseline: 9.3627x; 1.2584x over previous
//
#include <hip/hip_runtime.h>
#include <math.h>

// VolumeSDFRenderer — wave-per-ray, ZERO-LDS; absorb cascade via segmented
// shuffle ripple (bit-order-exact XLA base-16 two-level cumsum).
//
// R20 diagnosis: DS-pipe-bound (~67 DS instr/wave x 5.8cyc x 256 waves/CU
// ~= 41us, matching 38.7us; VALUBusy only 39%). This round halves DS ops:
//  * chunk sums S_0..S_6 AND L via ONE 7-step segmented shfl ripple:
//    lane 8c+j: P = fl(fl(P_{8c+j-1} + x0) + x1) — exactly the sequential
//    left-fold of the 16 chunk values (lane 63 adds x0 only -> P = L).
//    Replaces 2 ds_write + 31 ds_read with 7 shfl. No LDS array at all.
//  * P7 (seq scan of chunk sums) + per-lane chunk prefix from the SAME
//    7 __shfl gathers (capture running P7 at cc == myc-1).
//  * smooth excl = chunk_prefix + shfl_up(P,1): replaces the 7-op KS scan
//    AND now mirrors the reference's own two-level bracketing.
//  * znext via clamped global reload (VMEM has headroom) instead of shfl.
// DS ops/wave: 67 -> 33 (7 ripple + 7 gather + 1 PP + 18 butterfly).
//
// Absorb-critical semantics (proven R17-R20, absmax = bf16 floor 0.0039):
// element 127: y = fl(fl(L + x127) + P7), t = y - x127. PINs (asm value
// barriers) forbid -ffp-contract fma fusion (rounds 3-10's inf factory),
// (C+x)-x folding, and exp-arg distribution. __expf validated in R20.

#define N_PTS 128
#define PIN(v) asm volatile("" : "+v"(v))

__global__ __launch_bounds__(256) void vr21_ripple(
    const float* __restrict__ distance,
    const float* __restrict__ color,
    const float* __restrict__ depth,
    float* __restrict__ out,
    int n_rays)
{
    const int lane = threadIdx.x & 63;
    const int wv   = threadIdx.x >> 6;
    const int ray  = blockIdx.x * 4 + wv;
    if (ray >= n_rays) return;

    // ---- coalesced loads ----
    const float*  zrow  = depth + (size_t)ray * N_PTS;
    const float2* dist2 = (const float2*)(distance + (size_t)ray * N_PTS);
    const float2* dep2  = (const float2*)(zrow);
    float2 dv = dist2[lane];
    float2 zv = dep2[lane];
    float  z2 = zrow[(2 * lane + 2 < 128) ? (2 * lane + 2) : 127]; // depth[2l+2]

    // ---- density + x: same op ORDER as R17 (hw exp; PINned mul) ----
    float e0 = __expf(-150.0f * dv.x);
    float n0 = 150.0f * e0;
    float o0 = 1.0f + e0;
    float q0 = o0 * o0;
    float den0 = n0 / q0;                         // /inf -> +0 (np regime)

    float e1 = __expf(-150.0f * dv.y);
    float n1 = 150.0f * e1;
    float o1 = 1.0f + e1;
    float q1 = o1 * o1;
    float den1 = n1 / q1;

    float d0 = zv.y - zv.x;
    float d1 = (lane == 63) ? 1e10f : (z2 - zv.y);

    float x0 = d0 * den0; PIN(x0);                // no fma contraction
    float x1 = d1 * den1; PIN(x1);                // lane63: x127 (huge)

    // ---- segmented ripple: chunk sums (8 lanes = 16 pts per chunk) ----
    // After 7 steps: lane 8c+7 holds S_c (c<7), lane 63 holds L.
    float P = 0.0f;
    if ((lane & 7) == 0) {
        float a = x0;                             // 0 + x0 exact
        P = a + x1; PIN(P);                       // fl(x0+x1): seq order
    }
    #pragma unroll
    for (int j = 1; j < 8; ++j) {
        float v = __shfl_up(P, 1);
        if ((lane & 7) == j) {
            float a = v + x0; PIN(a);             // fl(P_prev + x0)
            if (lane == 63) {
                P = a;                            // L = seq(x112..x126)
            } else {
                P = a + x1; PIN(P);               // fl(.. + x1)
            }
        }
    }

    // ---- P7 (seq chunk-sum scan) + per-lane chunk prefix (same gathers) ---
    const int myc = lane >> 3;
    float P7 = 0.0f;
    float cpref = 0.0f;
    #pragma unroll
    for (int cc = 0; cc < 7; ++cc) {
        float Sc = __shfl(P, 8 * cc + 7);
        P7 = P7 + Sc; PIN(P7);
        if (myc == cc + 1) cpref = P7;            // seq prefix S0..S_{myc-1}
    }

    // ---- smooth exclusive prefix: two-level (matches ref bracketing) ----
    float PP = __shfl_up(P, 1);                   // within-chunk incl of l-1
    float wexcl = ((lane & 7) == 0) ? 0.0f : PP;
    float excl = cpref + wexcl;                   // sum x[0..2l-1] (smooth)

    // ---- weights ----
    float Ta = __expf(-excl);
    float E0 = __expf(-x0);
    float E1 = __expf(-x1);                       // lane63: exp(-x127)
    float Tb = Ta * E0;
    float wa = Ta * (1.0f - E0);
    float wb = Tb * (1.0f - E1);                  // lane63 overridden below

    // ---- element 127: y = fl(fl(L + x127) + P7), bit-order-exact ----
    {
        float y = P + x1; PIN(y);                 // lane63: L + x127
        y = y + P7;       PIN(y);                 // outer prefix: ONE add
        float t = y - x1; PIN(t);                 // opaque exp argument
        float T127 = __expf(-t);
        float w127 = T127 * (1.0f - E1);
        if (lane == 63) wb = w127;
    }

    // ---- color (3 ch x 2 pts = 3x float2 per lane) ----
    const float2* col2 = (const float2*)(color + (size_t)ray * 384 + lane * 6);
    float2 c0 = col2[0];
    float2 c1 = col2[1];
    float2 c2 = col2[2];
    float r = wa * c0.x + wb * c1.y;
    float g = wa * c0.y + wb * c2.x;
    float b = wa * c1.x + wb * c2.y;

    // ---- wave butterfly reduction ----
    #pragma unroll
    for (int off = 32; off >= 1; off >>= 1) {
        r += __shfl_xor(r, off);
        g += __shfl_xor(g, off);
        b += __shfl_xor(b, off);
    }

    if (lane == 0) {
        float* o = out + (size_t)ray * 3;
        o[0] = fminf(fmaxf(r, 0.0f), 2.5f);       // no-op clamp (sum w <= 2)
        o[1] = fminf(fmaxf(g, 0.0f), 2.5f);
        o[2] = fminf(fmaxf(b, 0.0f), 2.5f);
    }
}

extern "C" void kernel_launch(void* const* d_in, const int* in_sizes, int n_in,
                              void* d_out, int out_size, void* d_ws, size_t ws_size,
                              hipStream_t stream) {
    const float* distance = (const float*)d_in[0];
    const float* color    = (const float*)d_in[1];
    const float* depth    = (const float*)d_in[2];
    float* out = (float*)d_out;

    const int n_rays = in_sizes[0] / N_PTS;        // 65536
    const int blocks = (n_rays + 3) / 4;           // 4 rays (waves) / block

    hipLaunchKernelGGL(vr21_ripple, dim3(blocks), dim3(256), 0, stream,
                       distance, color, depth, out, n_rays);
}

// Round 22
// 30.265 us; speedup vs baseline: 9.5178x; 1.0166x over previous
//
#include <hip/hip_runtime.h>
#include <math.h>

// VolumeSDFRenderer — 32 lanes per ray (2 rays/wave), 4 points per lane.
// Absorb-critical XLA base-16 cascade kept bit-ORDER-exact (proven R17-R21,
// absmax pinned at the bf16 comparator floor 0.0039):
//   chunk sums: sequential 16-element fold = in-lane 4-add fold + 3-step
//   segmented ripple (4 lanes per chunk); lane q=31 stops at x126 -> L.
//   P7 = seq scan of S0..S6 (7 gathers); y = fl(fl(L+x127)+P7); t = y-x127.
//   PINs forbid -ffp-contract fma fusion (rounds 3-10's inf factory),
//   (C+x)-x folding, and exp-arg distribution.
//
// R21 -> R22 (R21 was DS+VALU balanced at ~190/~200 cyc per wave):
//  * 2 rays/wave: DS per ray ~2x down (ripple 7->3, butterfly 18->15,
//    all shuffle patterns stay within each 32-lane half).
//  * telescoped weights: w_p = exp(-cum_{p-1}) - exp(-cum_p) — one exp
//    per point instead of two (smooth diff ~1e-7 << 0.0392).
//  * density divide -> v_rcp_f32 (rcp(inf)=0 keeps the np /inf->+0 regime;
//    1-2 ulp class change validated by R20's __expf switch).

#define N_PTS 128
#define PIN(v) asm volatile("" : "+v"(v))

__global__ __launch_bounds__(256) void vr22_half(
    const float* __restrict__ distance,
    const float* __restrict__ color,
    const float* __restrict__ depth,
    float* __restrict__ out,
    int n_rays)
{
    const int lane = threadIdx.x & 63;
    const int wv   = threadIdx.x >> 6;
    const int h    = lane >> 5;               // half: ray select
    const int q    = lane & 31;               // lane within ray
    const int ray  = blockIdx.x * 8 + wv * 2 + h;
    if (ray >= n_rays) return;

    // ---- coalesced loads: 4 points per lane ----
    const float* zrow = depth + (size_t)ray * N_PTS;
    float4 dv = ((const float4*)(distance + (size_t)ray * N_PTS))[q];
    float4 zv = ((const float4*)zrow)[q];
    float  zb = zrow[(q < 31) ? (4 * q + 4) : 127];   // depth[4q+4]

    // ---- density (np op order; rcp keeps /inf -> +0) ----
    float e0 = __expf(-150.0f * dv.x), o0 = 1.0f + e0;
    float den0 = (150.0f * e0) * __builtin_amdgcn_rcpf(o0 * o0);
    float e1 = __expf(-150.0f * dv.y), o1 = 1.0f + e1;
    float den1 = (150.0f * e1) * __builtin_amdgcn_rcpf(o1 * o1);
    float e2 = __expf(-150.0f * dv.z), o2 = 1.0f + e2;
    float den2 = (150.0f * e2) * __builtin_amdgcn_rcpf(o2 * o2);
    float e3 = __expf(-150.0f * dv.w), o3 = 1.0f + e3;
    float den3 = (150.0f * e3) * __builtin_amdgcn_rcpf(o3 * o3);

    float d0 = zv.y - zv.x;
    float d1 = zv.z - zv.y;
    float d2 = zv.w - zv.z;
    float d3 = (q == 31) ? 1e10f : (zb - zv.w);

    float x0 = d0 * den0; PIN(x0);
    float x1 = d1 * den1; PIN(x1);
    float x2 = d2 * den2; PIN(x2);
    float x3 = d3 * den3; PIN(x3);            // q==31: x127 (huge)

    // ---- chunk sums: sequential 16-elem fold via in-lane fold + ripple ----
    float P;
    {
        float f = x0;                         // 0 + x0 exact
        f = f + x1; PIN(f);
        f = f + x2; PIN(f);
        float g2 = f + x3; PIN(g2);
        P = ((q & 3) == 0) ? g2 : 0.0f;       // chunk-head lanes initialized
    }
    #pragma unroll
    for (int j = 1; j < 4; ++j) {
        float v = __shfl_up(P, 1);            // same-half source (q&3>=1)
        if ((q & 3) == j) {
            float f = v + x0; PIN(f);
            f = f + x1; PIN(f);
            f = f + x2; PIN(f);
            if (q == 31) {
                P = f;                        // L = seq(x112..x126)
            } else {
                f = f + x3; PIN(f);
                P = f;                        // S_c at lane 4c+3
            }
        }
    }

    // ---- P7 (seq chunk-sum scan) + per-lane chunk prefix ----
    const int base = lane & 32;
    const int myc  = q >> 2;
    float P7 = 0.0f, cpref = 0.0f;
    #pragma unroll
    for (int cc = 0; cc < 7; ++cc) {
        float Sc = __shfl(P, base + 4 * cc + 3);
        P7 = P7 + Sc; PIN(P7);
        if (myc == cc + 1) cpref = P7;
    }

    // ---- smooth exclusive prefix (two-level, matches ref bracketing) ----
    float PP = __shfl_up(P, 1);
    float wexcl = ((q & 3) == 0) ? 0.0f : PP;
    float excl  = cpref + wexcl;

    // ---- telescoped weights: w_p = exp(-cum_{p-1}) - exp(-cum_p) ----
    float cum0 = excl + x0;
    float cum1 = cum0 + x1;
    float cum2 = cum1 + x2;
    float cum3 = cum2 + x3;                   // q==31: huge -> E3 = 0
    float F  = __expf(-excl);
    float E0 = __expf(-cum0);
    float E1 = __expf(-cum1);
    float E2 = __expf(-cum2);
    float E3 = __expf(-cum3);
    float w0 = F  - E0;
    float w1 = E0 - E1;
    float w2 = E1 - E2;
    float w3 = E2 - E3;

    // ---- element 127: bit-order-exact absorb chain (q==31) ----
    {
        float y = P + x3; PIN(y);             // L + x127 (junk on q!=31, finite)
        y = y + P7;       PIN(y);             // outer prefix: ONE add
        float t = y - x3; PIN(t);             // opaque exp argument
        float T127 = __expf(-t);
        float Ex   = __expf(-x3);
        float w127 = T127 * (1.0f - Ex);      // same formula/rounding as ref
        if (q == 31) w3 = w127;
    }

    // ---- color: 12 floats/lane = 3 float4 (48B-aligned) ----
    const float4* c4 = (const float4*)(color + (size_t)ray * 384 + q * 12);
    float4 ca = c4[0];   // p0.r p0.g p0.b p1.r
    float4 cb = c4[1];   // p1.g p1.b p2.r p2.g
    float4 cd = c4[2];   // p2.b p3.r p3.g p3.b
    float r = w0 * ca.x + w1 * ca.w + w2 * cb.z + w3 * cd.y;
    float g = w0 * ca.y + w1 * cb.x + w2 * cb.w + w3 * cd.z;
    float b = w0 * ca.z + w1 * cb.y + w2 * cd.x + w3 * cd.w;

    // ---- 32-lane butterfly (xor <= 16 stays within each half) ----
    #pragma unroll
    for (int off = 16; off >= 1; off >>= 1) {
        r += __shfl_xor(r, off);
        g += __shfl_xor(g, off);
        b += __shfl_xor(b, off);
    }

    if (q == 0) {
        float* o = out + (size_t)ray * 3;
        o[0] = fminf(fmaxf(r, 0.0f), 2.5f);   // no-op clamp (sum w <= 2)
        o[1] = fminf(fmaxf(g, 0.0f), 2.5f);
        o[2] = fminf(fmaxf(b, 0.0f), 2.5f);
    }
}

extern "C" void kernel_launch(void* const* d_in, const int* in_sizes, int n_in,
                              void* d_out, int out_size, void* d_ws, size_t ws_size,
                              hipStream_t stream) {
    const float* distance = (const float*)d_in[0];
    const float* color    = (const float*)d_in[1];
    const float* depth    = (const float*)d_in[2];
    float* out = (float*)d_out;

    const int n_rays = in_sizes[0] / N_PTS;        // 65536
    const int blocks = (n_rays + 7) / 8;           // 8 rays / 256-thread block

    hipLaunchKernelGGL(vr22_half, dim3(blocks), dim3(256), 0, stream,
                       distance, color, depth, out, n_rays);
}